// Round 2
// baseline (1410.539 us; speedup 1.0000x reference)
//
#include <hip/hip_runtime.h>
#include <math.h>

#define L_SEQ 2048
#define NCH   64      // scan chunks per sequence
#define LCH   32      // steps per chunk (NCH*LCH == L_SEQ)

__device__ __forceinline__ float sigmoidf_(float x){ return 1.f/(1.f+__expf(-x)); }

// ---------------------------------------------------------------------------
// C[M,N] = epi( A[M,K] @ W[N,K]^T + bias )
// A row-major with stride lda; optional per-batch row flip on A (seq reverse).
// EPI: 0 none, 1 +bias, 2 relu(+bias), 3 softplus(+bias)
// BM=BN=128, BK=8, 256 threads, 8x8 micro-tile (split fragments: rows/cols
// {t*4..t*4+3} and {64+t*4..64+t*4+3} -> 16B LDS lane stride = no 4-way bank
// conflict). Global->LDS is register-pipelined (prefetch next BK while
// computing current).
// ---------------------------------------------------------------------------
template<int EPI>
__global__ __launch_bounds__(256, 2)
void sgemm_nt(const float* __restrict__ A, int lda, int flipA,
              const float* __restrict__ W,
              const float* __restrict__ bias,
              float* __restrict__ C, int ldc,
              int M, int N, int K)
{
    __shared__ float As[8][132];
    __shared__ float Bs[8][132];
    const int tid = threadIdx.x;
    const int bm = blockIdx.y * 128;
    const int bn = blockIdx.x * 128;
    const int tx = tid & 15, ty = tid >> 4;
    const int l_r = tid >> 1;          // 0..127
    const int l_c = (tid & 1) * 4;     // 0 or 4

    int rowA = bm + l_r;
    if (flipA) rowA = (rowA & ~(L_SEQ-1)) | ((L_SEQ-1) - (rowA & (L_SEQ-1)));
    const float* Ap = A + (size_t)rowA * lda + l_c;
    const int wrow = bn + l_r;
    const bool wv = wrow < N;
    const float* Wp = W + (size_t)(wv ? wrow : 0) * K + l_c;

    float acc[8][8];
#pragma unroll
    for (int i=0;i<8;i++)
#pragma unroll
        for (int j=0;j<8;j++) acc[i][j]=0.f;

    // prefetch tile 0
    float4 av  = *(const float4*)(Ap);
    float4 wvv = wv ? *(const float4*)(Wp) : make_float4(0.f,0.f,0.f,0.f);

    for (int k0=0; k0<K; k0+=8){
        __syncthreads();   // previous compute done reading LDS
        As[l_c+0][l_r]=av.x;  As[l_c+1][l_r]=av.y;  As[l_c+2][l_r]=av.z;  As[l_c+3][l_r]=av.w;
        Bs[l_c+0][l_r]=wvv.x; Bs[l_c+1][l_r]=wvv.y; Bs[l_c+2][l_r]=wvv.z; Bs[l_c+3][l_r]=wvv.w;
        __syncthreads();
        if (k0 + 8 < K){   // issue next tile's global loads; latency hides under compute
            av  = *(const float4*)(Ap + k0 + 8);
            wvv = wv ? *(const float4*)(Wp + k0 + 8) : make_float4(0.f,0.f,0.f,0.f);
        }
#pragma unroll
        for (int kk=0;kk<8;kk++){
            float4 a0 = *(const float4*)&As[kk][ty*4];
            float4 a1 = *(const float4*)&As[kk][64+ty*4];
            float4 b0 = *(const float4*)&Bs[kk][tx*4];
            float4 b1 = *(const float4*)&Bs[kk][64+tx*4];
            float a_[8]={a0.x,a0.y,a0.z,a0.w,a1.x,a1.y,a1.z,a1.w};
            float b_[8]={b0.x,b0.y,b0.z,b0.w,b1.x,b1.y,b1.z,b1.w};
#pragma unroll
            for(int i=0;i<8;i++)
#pragma unroll
                for(int j=0;j<8;j++) acc[i][j] = fmaf(a_[i], b_[j], acc[i][j]);
        }
    }

#pragma unroll
    for (int i=0;i<8;i++){
        const int r = bm + ((i<4) ? (ty*4 + i) : (64 + ty*4 + (i-4)));
        float* crow = C + (size_t)r * ldc;
#pragma unroll
        for (int jj=0;jj<2;jj++){
            const int c = bn + ((jj==0) ? (tx*4) : (64 + tx*4));
            if (c < N){
                float vb[4];
#pragma unroll
                for (int u=0;u<4;u++){
                    float v = acc[i][jj*4+u];
                    if (EPI==1||EPI==2||EPI==3) v += bias[c+u];
                    if (EPI==2) v = fmaxf(v, 0.f);
                    if (EPI==3) v = fmaxf(v,0.f) + log1pf(__expf(-fabsf(v)));
                    vb[u]=v;
                }
                *(float4*)(crow + c) = make_float4(vb[0],vb[1],vb[2],vb[3]);
            }
        }
    }
}

// ---------------------------------------------------------------------------
// Causal depthwise conv1d (k=4, left pad 3) + SiLU.
// Input: xi-half (cols [0,1024)) of xz [4096, 2048]. Output xi [4096, 1024].
// ---------------------------------------------------------------------------
__global__ __launch_bounds__(256)
void conv_silu_k(const float* __restrict__ xz, const float* __restrict__ cw,
                 const float* __restrict__ cb, float* __restrict__ xi)
{
    const int d = blockIdx.x * 256 + threadIdx.x;   // 0..1023
    const int row = blockIdx.y;                     // 0..4095
    const int l = row & (L_SEQ-1);
    const float4 w4 = *(const float4*)(cw + d*4);
    const float wk[4] = {w4.x, w4.y, w4.z, w4.w};
    float acc = cb[d];
    const float* base = xz + (size_t)row * 2048 + d;
#pragma unroll
    for (int k=0;k<4;k++){
        const int ls = l - 3 + k;
        if (ls >= 0) acc = fmaf(wk[k], base[(k-3)*2048], acc);
    }
    xi[(size_t)row*1024 + d] = acc * sigmoidf_(acc);
}

// ---------------------------------------------------------------------------
// Scan pass 1: per-chunk summaries (Aprod, Bsum) for h_t = dA_t h_{t-1} + dBu_t
// dA = exp(delta*A), dBu = delta * B * xi.  Layout [b][chunk][d][n].
// ---------------------------------------------------------------------------
__global__ __launch_bounds__(256)
void scan_part1(const float* __restrict__ delta, const float* __restrict__ xi,
                const float* __restrict__ dbc, const float* __restrict__ A_log,
                float* __restrict__ Aprod, float* __restrict__ Bsum)
{
    const int d = blockIdx.x*256 + threadIdx.x;
    const int c = blockIdx.y;
    const int b = blockIdx.z;
    __shared__ float Bm[LCH][16];
    const int r0 = b*L_SEQ + c*LCH;
    for (int idx = threadIdx.x; idx < LCH*16; idx += 256){
        const int i = idx >> 4, n = idx & 15;
        Bm[i][n] = dbc[(size_t)(r0+i)*64 + 32 + n];
    }
    __syncthreads();
    float Ad[16];
#pragma unroll
    for (int n=0;n<16;n++) Ad[n] = -__expf(A_log[d*16+n]);
    float ap[16], bs[16];
#pragma unroll
    for (int n=0;n<16;n++){ ap[n]=1.f; bs[n]=0.f; }
    for (int i=0;i<LCH;i++){
        const size_t r = (size_t)(r0 + i);
        const float dl = delta[r*1024 + d];
        const float xv = xi[r*1024 + d];
        const float dx = dl * xv;
#pragma unroll
        for (int n=0;n<16;n++){
            const float da = __expf(dl * Ad[n]);
            bs[n] = fmaf(da, bs[n], dx * Bm[i][n]);
            ap[n] *= da;
        }
    }
    const size_t o = ((size_t)((b*NCH + c)*1024) + d) * 16;
#pragma unroll
    for (int n=0;n<16;n+=4){
        *(float4*)(Aprod + o + n) = make_float4(ap[n],ap[n+1],ap[n+2],ap[n+3]);
        *(float4*)(Bsum  + o + n) = make_float4(bs[n],bs[n+1],bs[n+2],bs[n+3]);
    }
}

// Pass 2: sequential combine across chunks -> state entering each chunk.
__global__ __launch_bounds__(256)
void scan_part2(const float* __restrict__ Aprod, const float* __restrict__ Bsum,
                float* __restrict__ hinit)
{
    const int g = blockIdx.x*256 + threadIdx.x;   // 32768 = B*1024*16
    const int n = g & 15; const int d = (g>>4) & 1023; const int b = g >> 14;
    float h = 0.f;
#pragma unroll 8
    for (int c=0;c<NCH;c++){
        const size_t o = ((size_t)((b*NCH + c)*1024) + d)*16 + n;
        const float a = Aprod[o];
        const float bb = Bsum[o];
        hinit[o] = h;
        h = fmaf(a, h, bb);
    }
}

// Pass 3: recompute local scan with initial state, produce y = (h.C + D*xi)*silu(z)
__global__ __launch_bounds__(256)
void scan_part3(const float* __restrict__ delta, const float* __restrict__ xi,
                const float* __restrict__ dbc, const float* __restrict__ xz,
                const float* __restrict__ A_log, const float* __restrict__ Dp,
                const float* __restrict__ hinit, float* __restrict__ y)
{
    const int d = blockIdx.x*256 + threadIdx.x;
    const int c = blockIdx.y;
    const int b = blockIdx.z;
    __shared__ float Bm[LCH][16], Cm[LCH][16];
    const int r0 = b*L_SEQ + c*LCH;
    for (int idx = threadIdx.x; idx < LCH*16; idx += 256){
        const int i = idx >> 4, n = idx & 15;
        const float* rowp = dbc + (size_t)(r0+i)*64;
        Bm[i][n] = rowp[32+n];
        Cm[i][n] = rowp[48+n];
    }
    __syncthreads();
    float Ad[16];
#pragma unroll
    for (int n=0;n<16;n++) Ad[n] = -__expf(A_log[d*16+n]);
    float h[16];
    const size_t ho = ((size_t)((b*NCH + c)*1024) + d)*16;
#pragma unroll
    for (int n=0;n<16;n++) h[n] = hinit[ho+n];
    const float Dd = Dp[d];
    for (int i=0;i<LCH;i++){
        const size_t r = (size_t)(r0 + i);
        const float dl = delta[r*1024 + d];
        const float xv = xi[r*1024 + d];
        const float dx = dl * xv;
        float yv = 0.f;
#pragma unroll
        for (int n=0;n<16;n++){
            const float da = __expf(dl * Ad[n]);
            h[n] = fmaf(da, h[n], dx * Bm[i][n]);
            yv = fmaf(h[n], Cm[i][n], yv);
        }
        yv = fmaf(Dd, xv, yv);
        const float zv = xz[r*2048 + 1024 + d];
        yv *= zv * sigmoidf_(zv);
        y[r*1024 + d] = yv;
    }
}

// ---------------------------------------------------------------------------
// out = [addafter +] LN( a(optionally seq-flipped) + res ) * w + b   over 512 cols
// ---------------------------------------------------------------------------
__global__ __launch_bounds__(128)
void ln_k(const float* __restrict__ a, int flipA, const float* __restrict__ res,
          const float* __restrict__ w, const float* __restrict__ bb,
          const float* __restrict__ addafter, float* __restrict__ out)
{
    const int row = blockIdx.x;
    const int tid = threadIdx.x;
    int ar = row;
    if (flipA) ar = (row & ~(L_SEQ-1)) | ((L_SEQ-1) - (row & (L_SEQ-1)));
    const int col = tid*4;
    const float4 av = *(const float4*)(a + (size_t)ar*512 + col);
    const float4 rv = *(const float4*)(res + (size_t)row*512 + col);
    const float v0=av.x+rv.x, v1=av.y+rv.y, v2=av.z+rv.z, v3=av.w+rv.w;
    float s  = v0+v1+v2+v3;
    float sq = v0*v0+v1*v1+v2*v2+v3*v3;
#pragma unroll
    for (int off=32; off>0; off>>=1){
        s  += __shfl_xor(s, off);
        sq += __shfl_xor(sq, off);
    }
    __shared__ float red[4];
    if ((tid & 63) == 0){ red[(tid>>6)*2] = s; red[(tid>>6)*2+1] = sq; }
    __syncthreads();
    s = red[0] + red[2]; sq = red[1] + red[3];
    const float mean = s * (1.f/512.f);
    const float var  = sq * (1.f/512.f) - mean*mean;
    const float rstd = rsqrtf(var + 1e-5f);
    const float4 wv = *(const float4*)(w + col);
    const float4 bv = *(const float4*)(bb + col);
    float o0 = (v0-mean)*rstd*wv.x + bv.x;
    float o1 = (v1-mean)*rstd*wv.y + bv.y;
    float o2 = (v2-mean)*rstd*wv.z + bv.z;
    float o3 = (v3-mean)*rstd*wv.w + bv.w;
    if (addafter){
        const float4 xv = *(const float4*)(addafter + (size_t)row*512 + col);
        o0 += xv.x; o1 += xv.y; o2 += xv.z; o3 += xv.w;
    }
    *(float4*)(out + (size_t)row*512 + col) = make_float4(o0,o1,o2,o3);
}

// ---------------------------------------------------------------------------
extern "C" void kernel_launch(void* const* d_in, const int* in_sizes, int n_in,
                              void* d_out, int out_size, void* d_ws, size_t ws_size,
                              hipStream_t stream)
{
    const float* x = (const float*)d_in[0];
    struct DirP { const float *in_w,*conv_w,*conv_b,*xproj_w,*dt_w,*dt_b,*A_log,*D,*out_w; };
    DirP dp[2];
    for (int p=0;p<2;p++){
        const int b = 1 + p*9;
        dp[p].in_w    = (const float*)d_in[b+0];
        dp[p].conv_w  = (const float*)d_in[b+1];
        dp[p].conv_b  = (const float*)d_in[b+2];
        dp[p].xproj_w = (const float*)d_in[b+3];
        dp[p].dt_w    = (const float*)d_in[b+4];
        dp[p].dt_b    = (const float*)d_in[b+5];
        dp[p].A_log   = (const float*)d_in[b+6];
        dp[p].D       = (const float*)d_in[b+7];
        dp[p].out_w   = (const float*)d_in[b+8];
    }
    const float* lnw[4]; const float* lnb[4];
    for (int i=0;i<4;i++){ lnw[i]=(const float*)d_in[19+2*i]; lnb[i]=(const float*)d_in[20+2*i]; }
    const float* f1w1=(const float*)d_in[27]; const float* f1b1=(const float*)d_in[28];
    const float* f1w2=(const float*)d_in[29]; const float* f1b2=(const float*)d_in[30];
    const float* f2w1=(const float*)d_in[31]; const float* f2b1=(const float*)d_in[32];
    const float* f2w2=(const float*)d_in[33]; const float* f2b2=(const float*)d_in[34];

    float* ws = (float*)d_ws;
    size_t o = 0;
    auto alloc = [&](size_t n){ float* p = ws + o; o += n; return p; };
    const size_t M = 4096;
    float* xz    = alloc(M*2048);
    float* xi    = alloc(M*1024);
    float* dbc   = alloc(M*64);
    float* delta = alloc(M*1024);
    float* yb    = alloc(M*1024);
    float* Aprod = alloc((size_t)2*NCH*1024*16);
    float* Bsum  = alloc((size_t)2*NCH*1024*16);
    float* hinit = alloc((size_t)2*NCH*1024*16);
    float* mamba = alloc(M*512);
    float* xf1   = alloc(M*512);
    float* xf2   = alloc(M*512);
    float* xb1   = alloc(M*512);
    float* ffh   = alloc(M*1024);
    float* ffo   = alloc(M*512);
    (void)ws_size; (void)in_sizes; (void)n_in; (void)out_size;

    const dim3 blk(256);
    auto ggrid = [](int N){ return dim3((unsigned)((N+127)/128), 32); };

    for (int p=0;p<2;p++){
        const DirP& d = dp[p];
        // in_proj (flip rows for backward direction)
        sgemm_nt<0><<<ggrid(2048), blk, 0, stream>>>(x, 512, p, d.in_w, nullptr, xz, 2048, 4096, 2048, 512);
        // causal depthwise conv + silu
        conv_silu_k<<<dim3(4,4096), blk, 0, stream>>>(xz, d.conv_w, d.conv_b, xi);
        // x_proj -> [delta_r | B | C]
        sgemm_nt<0><<<ggrid(64), blk, 0, stream>>>(xi, 1024, 0, d.xproj_w, nullptr, dbc, 64, 4096, 64, 1024);
        // dt_proj + softplus (reads only first 32 cols of dbc via K=32)
        sgemm_nt<3><<<ggrid(1024), blk, 0, stream>>>(dbc, 64, 0, d.dt_w, d.dt_b, delta, 1024, 4096, 1024, 32);
        // chunked associative scan
        scan_part1<<<dim3(4,NCH,2), blk, 0, stream>>>(delta, xi, dbc, d.A_log, Aprod, Bsum);
        scan_part2<<<dim3(128), blk, 0, stream>>>(Aprod, Bsum, hinit);
        scan_part3<<<dim3(4,NCH,2), blk, 0, stream>>>(delta, xi, dbc, xz, d.A_log, d.D, hinit, yb);
        // out_proj
        sgemm_nt<0><<<ggrid(512), blk, 0, stream>>>(yb, 1024, 0, d.out_w, nullptr, mamba, 512, 4096, 512, 1024);
        if (p==0){
            ln_k<<<4096,128,0,stream>>>(mamba, 0, x, lnw[0], lnb[0], nullptr, xf1);
            sgemm_nt<2><<<ggrid(1024), blk,0,stream>>>(xf1, 512, 0, f1w1, f1b1, ffh, 1024, 4096, 1024, 512);
            sgemm_nt<1><<<ggrid(512),  blk,0,stream>>>(ffh, 1024, 0, f1w2, f1b2, ffo, 512, 4096, 512, 1024);
            ln_k<<<4096,128,0,stream>>>(ffo, 0, xf1, lnw[1], lnb[1], nullptr, xf2);
        } else {
            ln_k<<<4096,128,0,stream>>>(mamba, 1, x, lnw[2], lnb[2], nullptr, xb1);
            // NOTE: faithful to reference bug — ffn2 consumes x_f2, not x_b
            sgemm_nt<2><<<ggrid(1024), blk,0,stream>>>(xf2, 512, 0, f2w1, f2b1, ffh, 1024, 4096, 1024, 512);
            sgemm_nt<1><<<ggrid(512),  blk,0,stream>>>(ffh, 1024, 0, f2w2, f2b2, ffo, 512, 4096, 512, 1024);
            // x_b2 = LN(ffo + x_b1); final out = x_f2 + x_b2 (fused)
            ln_k<<<4096,128,0,stream>>>(ffo, 0, xb1, lnw[3], lnb[3], xf2, (float*)d_out);
        }
    }
}

// Round 3
// 762.707 us; speedup vs baseline: 1.8494x; 1.8494x over previous
//
#include <hip/hip_runtime.h>
#include <math.h>

#define L_SEQ 2048
#define NCH   64      // scan chunks per sequence
#define LCH   32      // steps per chunk (NCH*LCH == L_SEQ)

using bf16x8 = __attribute__((ext_vector_type(8))) short;
using f32x4  = __attribute__((ext_vector_type(4))) float;

__device__ __forceinline__ float sigmoidf_(float x){ return 1.f/(1.f+__expf(-x)); }

// split-bf16 helpers: hi = truncate-to-bf16(a) (exact in bf16), lo = bf16(a - hi).
// combined input precision ~2^-16 relative -> GEMM results match fp32 to ~1e-5 rel.
__device__ __forceinline__ unsigned pack_hi2(float a, float b){
    return (__float_as_uint(a)>>16) | (__float_as_uint(b) & 0xffff0000u);
}
__device__ __forceinline__ float hi_part(float a){
    return __uint_as_float(__float_as_uint(a) & 0xffff0000u);
}

// ---------------------------------------------------------------------------
// C[M,N] = epi( A[M,K] @ W[N,K]^T + bias )  via split-bf16 MFMA (3 products).
// A fp32 row-major (stride lda), optional per-batch seq flip. W fp32 [N,K].
// Tile: BM = MWF*32 (2 waves in M), BN = 128 (2 waves in N), BK = 32.
// 256 threads = 4 waves, wave tile (MWF*16) x 64, 16x16x32 bf16 MFMA frags.
// LDS rows = 128B (32 hi bf16 | 32 lo bf16), slot-swizzled: slot ^= (row&7)
// -> conflict-free ds_write_b64 staging and ds_read_b128 fragment reads.
// EPI: 0 none, 1 +bias, 2 relu(+bias), 3 softplus(+bias)
// ---------------------------------------------------------------------------
template<int EPI, int MWF>
__global__ __launch_bounds__(256, 2)
void mgemm_nt(const float* __restrict__ A, int lda, int flipA,
              const float* __restrict__ W,
              const float* __restrict__ bias,
              float* __restrict__ C, int ldc,
              int M, int N, int K)
{
    __shared__ char smem[MWF*4096 + 16384];     // A: MWF*4KB, B: 16KB
    char* As = smem;
    char* Bs = smem + MWF*4096;

    const int tid = threadIdx.x;
    const int bm = blockIdx.y * (MWF*32);
    const int bn = blockIdx.x * 128;

    // ---- staging assignment: q = float4-column (0..7) within a 32-float row,
    //      rows r0s + 32*i  (i < MWF for A, i < 4 for B)
    const int q   = tid & 7;
    const int r0s = tid >> 3;            // 0..31
    const int g8  = r0s & 7;             // (row & 7), constant across i
    const int wbase = r0s*128 + (((q>>1) ^ g8) << 4) + (q&1)*8;

    const float* aptr[MWF];
#pragma unroll
    for (int i=0;i<MWF;i++){
        int rr = bm + r0s + 32*i;
        if (flipA) rr = (rr & ~(L_SEQ-1)) | ((L_SEQ-1) - (rr & (L_SEQ-1)));
        aptr[i] = A + (size_t)rr*lda + q*4;
    }
    const float* wptr[4]; bool wval[4];
#pragma unroll
    for (int i=0;i<4;i++){
        const int wr = bn + r0s + 32*i;
        wval[i] = wr < N;
        wptr[i] = W + (size_t)(wval[i] ? wr : 0)*K + q*4;
    }

    // ---- fragment read offsets
    const int lane = tid & 63;
    const int wid  = tid >> 6;
    const int wm = wid >> 1, wn = wid & 1;
    const int fr = lane & 15;            // row/col within 16-frag
    const int kh = lane >> 4;            // which 8-element k group
    const int rslot = (kh ^ (fr & 7)) << 4;
    int aro[MWF], bro[4];
#pragma unroll
    for (int mf=0; mf<MWF; mf++) aro[mf] = (wm*(MWF*16) + mf*16 + fr)*128 + rslot;
#pragma unroll
    for (int nf=0; nf<4;   nf++) bro[nf] = (wn*64      + nf*16 + fr)*128 + rslot;

    f32x4 acc[MWF][4];
#pragma unroll
    for (int i=0;i<MWF;i++)
#pragma unroll
        for (int j=0;j<4;j++) acc[i][j] = (f32x4){0.f,0.f,0.f,0.f};

    float4 ra[MWF], rb[4];
#pragma unroll
    for (int i=0;i<MWF;i++) ra[i] = *(const float4*)(aptr[i]);
#pragma unroll
    for (int i=0;i<4;i++)  rb[i] = wval[i] ? *(const float4*)(wptr[i]) : make_float4(0,0,0,0);

    for (int k0=0; k0<K; k0+=32){
        __syncthreads();                     // previous compute done with LDS
        // convert + stage (hi plane at slot, lo plane at slot^4 == offset^64)
#pragma unroll
        for (int i=0;i<MWF;i++){
            const float4 v = ra[i];
            uint2 h, l;
            h.x = pack_hi2(v.x, v.y); h.y = pack_hi2(v.z, v.w);
            const float lx = v.x-hi_part(v.x), ly = v.y-hi_part(v.y);
            const float lz = v.z-hi_part(v.z), lw = v.w-hi_part(v.w);
            l.x = pack_hi2(lx, ly); l.y = pack_hi2(lz, lw);
            *(uint2*)(As + (wbase + i*4096))      = h;
            *(uint2*)(As + ((wbase + i*4096)^64)) = l;
        }
#pragma unroll
        for (int i=0;i<4;i++){
            const float4 v = rb[i];
            uint2 h, l;
            h.x = pack_hi2(v.x, v.y); h.y = pack_hi2(v.z, v.w);
            const float lx = v.x-hi_part(v.x), ly = v.y-hi_part(v.y);
            const float lz = v.z-hi_part(v.z), lw = v.w-hi_part(v.w);
            l.x = pack_hi2(lx, ly); l.y = pack_hi2(lz, lw);
            *(uint2*)(Bs + (wbase + i*4096))      = h;
            *(uint2*)(Bs + ((wbase + i*4096)^64)) = l;
        }
        __syncthreads();                     // tile ready
        if (k0 + 32 < K){                    // prefetch next tile (hides under MFMA)
#pragma unroll
            for (int i=0;i<MWF;i++) ra[i] = *(const float4*)(aptr[i] + k0 + 32);
#pragma unroll
            for (int i=0;i<4;i++)  rb[i] = wval[i] ? *(const float4*)(wptr[i] + k0 + 32)
                                                   : make_float4(0,0,0,0);
        }
        bf16x8 ah[MWF], al[MWF], bh[4], bl[4];
#pragma unroll
        for (int t=0;t<MWF;t++){
            ah[t] = *(const bf16x8*)(As + aro[t]);
            al[t] = *(const bf16x8*)(As + (aro[t]^64));
        }
#pragma unroll
        for (int t=0;t<4;t++){
            bh[t] = *(const bf16x8*)(Bs + bro[t]);
            bl[t] = *(const bf16x8*)(Bs + (bro[t]^64));
        }
#pragma unroll
        for (int mf=0;mf<MWF;mf++)
#pragma unroll
            for (int nf=0;nf<4;nf++){
                acc[mf][nf] = __builtin_amdgcn_mfma_f32_16x16x32_bf16(ah[mf], bh[nf], acc[mf][nf], 0,0,0);
                acc[mf][nf] = __builtin_amdgcn_mfma_f32_16x16x32_bf16(ah[mf], bl[nf], acc[mf][nf], 0,0,0);
                acc[mf][nf] = __builtin_amdgcn_mfma_f32_16x16x32_bf16(al[mf], bh[nf], acc[mf][nf], 0,0,0);
            }
    }

    // ---- epilogue: D layout col=lane&15, row=(lane>>4)*4+reg  [m89-verified]
#pragma unroll
    for (int mf=0; mf<MWF; mf++){
        const int grow = bm + wm*(MWF*16) + mf*16 + kh*4;
#pragma unroll
        for (int nf=0; nf<4; nf++){
            const int gcol = bn + wn*64 + nf*16 + fr;
            if (gcol < N){
                const float bv = (EPI>=1) ? bias[gcol] : 0.f;
#pragma unroll
                for (int j=0;j<4;j++){
                    float v = acc[mf][nf][j] + bv;
                    if (EPI==2) v = fmaxf(v, 0.f);
                    if (EPI==3) v = fmaxf(v,0.f) + log1pf(__expf(-fabsf(v)));
                    C[(size_t)(grow+j)*ldc + gcol] = v;
                }
            }
        }
    }
}

// ---------------------------------------------------------------------------
// Causal depthwise conv1d (k=4, left pad 3) + SiLU.
// ---------------------------------------------------------------------------
__global__ __launch_bounds__(256)
void conv_silu_k(const float* __restrict__ xz, const float* __restrict__ cw,
                 const float* __restrict__ cb, float* __restrict__ xi)
{
    const int d = blockIdx.x * 256 + threadIdx.x;   // 0..1023
    const int row = blockIdx.y;                     // 0..4095
    const int l = row & (L_SEQ-1);
    const float4 w4 = *(const float4*)(cw + d*4);
    const float wk[4] = {w4.x, w4.y, w4.z, w4.w};
    float acc = cb[d];
    const float* base = xz + (size_t)row * 2048 + d;
#pragma unroll
    for (int k=0;k<4;k++){
        const int ls = l - 3 + k;
        if (ls >= 0) acc = fmaf(wk[k], base[(k-3)*2048], acc);
    }
    xi[(size_t)row*1024 + d] = acc * sigmoidf_(acc);
}

// ---------------------------------------------------------------------------
// Scan pass 1: per-chunk summaries (Aprod, Bsum) of h_t = dA_t h_{t-1} + dBu_t
// ---------------------------------------------------------------------------
__global__ __launch_bounds__(256)
void scan_part1(const float* __restrict__ delta, const float* __restrict__ xi,
                const float* __restrict__ dbc, const float* __restrict__ A_log,
                float* __restrict__ Aprod, float* __restrict__ Bsum)
{
    const int d = blockIdx.x*256 + threadIdx.x;
    const int c = blockIdx.y;
    const int b = blockIdx.z;
    __shared__ float Bm[LCH][16];
    const int r0 = b*L_SEQ + c*LCH;
    for (int idx = threadIdx.x; idx < LCH*16; idx += 256){
        const int i = idx >> 4, n = idx & 15;
        Bm[i][n] = dbc[(size_t)(r0+i)*64 + 32 + n];
    }
    __syncthreads();
    float Ad[16];
#pragma unroll
    for (int n=0;n<16;n++) Ad[n] = -__expf(A_log[d*16+n]);
    float ap[16], bs[16];
#pragma unroll
    for (int n=0;n<16;n++){ ap[n]=1.f; bs[n]=0.f; }
    for (int i=0;i<LCH;i++){
        const size_t r = (size_t)(r0 + i);
        const float dl = delta[r*1024 + d];
        const float xv = xi[r*1024 + d];
        const float dx = dl * xv;
#pragma unroll
        for (int n=0;n<16;n++){
            const float da = __expf(dl * Ad[n]);
            bs[n] = fmaf(da, bs[n], dx * Bm[i][n]);
            ap[n] *= da;
        }
    }
    const size_t o = ((size_t)((b*NCH + c)*1024) + d) * 16;
#pragma unroll
    for (int n=0;n<16;n+=4){
        *(float4*)(Aprod + o + n) = make_float4(ap[n],ap[n+1],ap[n+2],ap[n+3]);
        *(float4*)(Bsum  + o + n) = make_float4(bs[n],bs[n+1],bs[n+2],bs[n+3]);
    }
}

// Pass 2: sequential combine across chunks -> state entering each chunk.
__global__ __launch_bounds__(256)
void scan_part2(const float* __restrict__ Aprod, const float* __restrict__ Bsum,
                float* __restrict__ hinit)
{
    const int g = blockIdx.x*256 + threadIdx.x;   // 32768 = B*1024*16
    const int n = g & 15; const int d = (g>>4) & 1023; const int b = g >> 14;
    float h = 0.f;
#pragma unroll 8
    for (int c=0;c<NCH;c++){
        const size_t o = ((size_t)((b*NCH + c)*1024) + d)*16 + n;
        const float a = Aprod[o];
        const float bb = Bsum[o];
        hinit[o] = h;
        h = fmaf(a, h, bb);
    }
}

// Pass 3: recompute local scan with initial state, y = (h.C + D*xi)*silu(z)
__global__ __launch_bounds__(256)
void scan_part3(const float* __restrict__ delta, const float* __restrict__ xi,
                const float* __restrict__ dbc, const float* __restrict__ xz,
                const float* __restrict__ A_log, const float* __restrict__ Dp,
                const float* __restrict__ hinit, float* __restrict__ y)
{
    const int d = blockIdx.x*256 + threadIdx.x;
    const int c = blockIdx.y;
    const int b = blockIdx.z;
    __shared__ float Bm[LCH][16], Cm[LCH][16];
    const int r0 = b*L_SEQ + c*LCH;
    for (int idx = threadIdx.x; idx < LCH*16; idx += 256){
        const int i = idx >> 4, n = idx & 15;
        const float* rowp = dbc + (size_t)(r0+i)*64;
        Bm[i][n] = rowp[32+n];
        Cm[i][n] = rowp[48+n];
    }
    __syncthreads();
    float Ad[16];
#pragma unroll
    for (int n=0;n<16;n++) Ad[n] = -__expf(A_log[d*16+n]);
    float h[16];
    const size_t ho = ((size_t)((b*NCH + c)*1024) + d)*16;
#pragma unroll
    for (int n=0;n<16;n++) h[n] = hinit[ho+n];
    const float Dd = Dp[d];
    for (int i=0;i<LCH;i++){
        const size_t r = (size_t)(r0 + i);
        const float dl = delta[r*1024 + d];
        const float xv = xi[r*1024 + d];
        const float dx = dl * xv;
        float yv = 0.f;
#pragma unroll
        for (int n=0;n<16;n++){
            const float da = __expf(dl * Ad[n]);
            h[n] = fmaf(da, h[n], dx * Bm[i][n]);
            yv = fmaf(h[n], Cm[i][n], yv);
        }
        yv = fmaf(Dd, xv, yv);
        const float zv = xz[r*2048 + 1024 + d];
        yv *= zv * sigmoidf_(zv);
        y[r*1024 + d] = yv;
    }
}

// ---------------------------------------------------------------------------
// out = [addafter +] LN( a(optionally seq-flipped) + res ) * w + b  (512 cols)
// ---------------------------------------------------------------------------
__global__ __launch_bounds__(128)
void ln_k(const float* __restrict__ a, int flipA, const float* __restrict__ res,
          const float* __restrict__ w, const float* __restrict__ bb,
          const float* __restrict__ addafter, float* __restrict__ out)
{
    const int row = blockIdx.x;
    const int tid = threadIdx.x;
    int ar = row;
    if (flipA) ar = (row & ~(L_SEQ-1)) | ((L_SEQ-1) - (row & (L_SEQ-1)));
    const int col = tid*4;
    const float4 av = *(const float4*)(a + (size_t)ar*512 + col);
    const float4 rv = *(const float4*)(res + (size_t)row*512 + col);
    const float v0=av.x+rv.x, v1=av.y+rv.y, v2=av.z+rv.z, v3=av.w+rv.w;
    float s  = v0+v1+v2+v3;
    float sq = v0*v0+v1*v1+v2*v2+v3*v3;
#pragma unroll
    for (int off=32; off>0; off>>=1){
        s  += __shfl_xor(s, off);
        sq += __shfl_xor(sq, off);
    }
    __shared__ float red[4];
    if ((tid & 63) == 0){ red[(tid>>6)*2] = s; red[(tid>>6)*2+1] = sq; }
    __syncthreads();
    s = red[0] + red[2]; sq = red[1] + red[3];
    const float mean = s * (1.f/512.f);
    const float var  = sq * (1.f/512.f) - mean*mean;
    const float rstd = rsqrtf(var + 1e-5f);
    const float4 wv = *(const float4*)(w + col);
    const float4 bv = *(const float4*)(bb + col);
    float o0 = (v0-mean)*rstd*wv.x + bv.x;
    float o1 = (v1-mean)*rstd*wv.y + bv.y;
    float o2 = (v2-mean)*rstd*wv.z + bv.z;
    float o3 = (v3-mean)*rstd*wv.w + bv.w;
    if (addafter){
        const float4 xv = *(const float4*)(addafter + (size_t)row*512 + col);
        o0 += xv.x; o1 += xv.y; o2 += xv.z; o3 += xv.w;
    }
    *(float4*)(out + (size_t)row*512 + col) = make_float4(o0,o1,o2,o3);
}

// ---------------------------------------------------------------------------
extern "C" void kernel_launch(void* const* d_in, const int* in_sizes, int n_in,
                              void* d_out, int out_size, void* d_ws, size_t ws_size,
                              hipStream_t stream)
{
    const float* x = (const float*)d_in[0];
    struct DirP { const float *in_w,*conv_w,*conv_b,*xproj_w,*dt_w,*dt_b,*A_log,*D,*out_w; };
    DirP dp[2];
    for (int p=0;p<2;p++){
        const int b = 1 + p*9;
        dp[p].in_w    = (const float*)d_in[b+0];
        dp[p].conv_w  = (const float*)d_in[b+1];
        dp[p].conv_b  = (const float*)d_in[b+2];
        dp[p].xproj_w = (const float*)d_in[b+3];
        dp[p].dt_w    = (const float*)d_in[b+4];
        dp[p].dt_b    = (const float*)d_in[b+5];
        dp[p].A_log   = (const float*)d_in[b+6];
        dp[p].D       = (const float*)d_in[b+7];
        dp[p].out_w   = (const float*)d_in[b+8];
    }
    const float* lnw[4]; const float* lnb[4];
    for (int i=0;i<4;i++){ lnw[i]=(const float*)d_in[19+2*i]; lnb[i]=(const float*)d_in[20+2*i]; }
    const float* f1w1=(const float*)d_in[27]; const float* f1b1=(const float*)d_in[28];
    const float* f1w2=(const float*)d_in[29]; const float* f1b2=(const float*)d_in[30];
    const float* f2w1=(const float*)d_in[31]; const float* f2b1=(const float*)d_in[32];
    const float* f2w2=(const float*)d_in[33]; const float* f2b2=(const float*)d_in[34];

    float* ws = (float*)d_ws;
    size_t o = 0;
    auto alloc = [&](size_t n){ float* p = ws + o; o += n; return p; };
    const size_t M = 4096;
    float* xz    = alloc(M*2048);
    float* xi    = alloc(M*1024);
    float* dbc   = alloc(M*64);
    float* delta = alloc(M*1024);
    float* yb    = alloc(M*1024);
    float* Aprod = alloc((size_t)2*NCH*1024*16);
    float* Bsum  = alloc((size_t)2*NCH*1024*16);
    float* hinit = alloc((size_t)2*NCH*1024*16);
    float* mamba = alloc(M*512);
    float* xf1   = alloc(M*512);
    float* xf2   = alloc(M*512);
    float* xb1   = alloc(M*512);
    float* ffh   = alloc(M*1024);
    float* ffo   = alloc(M*512);
    (void)ws_size; (void)in_sizes; (void)n_in; (void)out_size;

    const dim3 blk(256);
    // grids: (N/128 cols, M/(MWF*32) rows)
    const dim3 g_in (16, 32);   // N=2048, MWF=4
    const dim3 g_xp ( 1, 64);   // N=64,   MWF=2
    const dim3 g_dt ( 8, 32);   // N=1024, MWF=4
    const dim3 g_out( 4, 64);   // N=512,  MWF=2
    const dim3 g_f1 ( 8, 32);   // N=1024, MWF=4
    const dim3 g_f2 ( 4, 64);   // N=512,  MWF=2

    for (int p=0;p<2;p++){
        const DirP& d = dp[p];
        // in_proj (flip rows for backward direction)
        mgemm_nt<0,4><<<g_in, blk, 0, stream>>>(x, 512, p, d.in_w, nullptr, xz, 2048, 4096, 2048, 512);
        // causal depthwise conv + silu
        conv_silu_k<<<dim3(4,4096), blk, 0, stream>>>(xz, d.conv_w, d.conv_b, xi);
        // x_proj -> [delta_r | B | C]
        mgemm_nt<0,2><<<g_xp, blk, 0, stream>>>(xi, 1024, 0, d.xproj_w, nullptr, dbc, 64, 4096, 64, 1024);
        // dt_proj + softplus (reads first 32 cols of dbc via K=32)
        mgemm_nt<3,4><<<g_dt, blk, 0, stream>>>(dbc, 64, 0, d.dt_w, d.dt_b, delta, 1024, 4096, 1024, 32);
        // chunked associative scan
        scan_part1<<<dim3(4,NCH,2), blk, 0, stream>>>(delta, xi, dbc, d.A_log, Aprod, Bsum);
        scan_part2<<<dim3(128), blk, 0, stream>>>(Aprod, Bsum, hinit);
        scan_part3<<<dim3(4,NCH,2), blk, 0, stream>>>(delta, xi, dbc, xz, d.A_log, d.D, hinit, yb);
        // out_proj
        mgemm_nt<0,2><<<g_out, blk, 0, stream>>>(yb, 1024, 0, d.out_w, nullptr, mamba, 512, 4096, 512, 1024);
        if (p==0){
            ln_k<<<4096,128,0,stream>>>(mamba, 0, x, lnw[0], lnb[0], nullptr, xf1);
            mgemm_nt<2,4><<<g_f1, blk,0,stream>>>(xf1, 512, 0, f1w1, f1b1, ffh, 1024, 4096, 1024, 512);
            mgemm_nt<1,2><<<g_f2, blk,0,stream>>>(ffh, 1024, 0, f1w2, f1b2, ffo, 512, 4096, 512, 1024);
            ln_k<<<4096,128,0,stream>>>(ffo, 0, xf1, lnw[1], lnb[1], nullptr, xf2);
        } else {
            ln_k<<<4096,128,0,stream>>>(mamba, 1, x, lnw[2], lnb[2], nullptr, xb1);
            // NOTE: faithful to reference bug — ffn2 consumes x_f2, not x_b
            mgemm_nt<2,4><<<g_f1, blk,0,stream>>>(xf2, 512, 0, f2w1, f2b1, ffh, 1024, 4096, 1024, 512);
            mgemm_nt<1,2><<<g_f2, blk,0,stream>>>(ffh, 1024, 0, f2w2, f2b2, ffo, 512, 4096, 512, 1024);
            // x_b2 = LN(ffo + x_b1); final out = x_f2 + x_b2 (fused)
            ln_k<<<4096,128,0,stream>>>(ffo, 0, xb1, lnw[3], lnb[3], xf2, (float*)d_out);
        }
    }
}